// Round 3
// baseline (378.747 us; speedup 1.0000x reference)
//
#include <hip/hip_runtime.h>
#include <hip/hip_bf16.h>
#include <stdint.h>

#define S_LEN 1024
#define E_DIM 768
#define H_N   12
#define FF_DIM 3072

typedef __hip_bfloat16 bf16;
using short8  = __attribute__((ext_vector_type(8))) short;
using short4v = __attribute__((ext_vector_type(4))) short;
using f32x4   = __attribute__((ext_vector_type(4))) float;

__device__ __forceinline__ void async_cp16(const void* g, void* l) {
  __builtin_amdgcn_global_load_lds(
      (__attribute__((address_space(1))) void*)(g),
      (__attribute__((address_space(3))) void*)(l), 16, 0, 0);
}

// -------- fused weight transpose + cast (all 4 weights, one launch) ----------
__global__ __launch_bounds__(256) void wcastT_all(
    const float* __restrict__ wa, const float* __restrict__ wp,
    const float* __restrict__ wf, const float* __restrict__ wf2,
    bf16* __restrict__ oa, bf16* __restrict__ op,
    bf16* __restrict__ of, bf16* __restrict__ of2) {
  __shared__ float t[32][33];
  int bid = blockIdx.x;
  const float* w; bf16* wt; int K, N, bx, by;
  if (bid < 1728)      { w = wa;  wt = oa;  K = 768;  N = 2304; int r = bid;        bx = r % 72; by = r / 72; }
  else if (bid < 2304) { w = wp;  wt = op;  K = 768;  N = 768;  int r = bid - 1728; bx = r % 24; by = r / 24; }
  else if (bid < 4608) { w = wf;  wt = of;  K = 768;  N = 3072; int r = bid - 2304; bx = r % 96; by = r / 96; }
  else                 { w = wf2; wt = of2; K = 3072; N = 768;  int r = bid - 4608; bx = r % 24; by = r / 24; }
  int x = threadIdx.x & 31;
  int y = threadIdx.x >> 5;     // 0..7
  for (int i = y; i < 32; i += 8)
    t[i][x] = w[(size_t)(by * 32 + i) * N + bx * 32 + x];
  __syncthreads();
  for (int i = y; i < 32; i += 8)
    wt[(size_t)(bx * 32 + i) * K + by * 32 + x] = __float2bfloat16(t[x][i]);
}

// ---------------- layernorm over E=768, out bf16 -----------------------------
__global__ __launch_bounds__(256) void ln_rows(const float* __restrict__ x,
                                               const float* __restrict__ g,
                                               const float* __restrict__ b,
                                               bf16* __restrict__ out) {
  int row = blockIdx.x;
  int tid = threadIdx.x;
  const float* xr = x + (size_t)row * E_DIM;
  float v0 = xr[tid], v1 = xr[tid + 256], v2 = xr[tid + 512];
  float s = v0 + v1 + v2;
  float ss = v0 * v0 + v1 * v1 + v2 * v2;
  for (int o = 32; o > 0; o >>= 1) {
    s  += __shfl_down(s, o);
    ss += __shfl_down(ss, o);
  }
  __shared__ float ps[4], pq[4];
  int wv = tid >> 6;
  if ((tid & 63) == 0) { ps[wv] = s; pq[wv] = ss; }
  __syncthreads();
  s  = ps[0] + ps[1] + ps[2] + ps[3];
  ss = pq[0] + pq[1] + pq[2] + pq[3];
  float mu  = s * (1.0f / E_DIM);
  float var = ss * (1.0f / E_DIM) - mu * mu;
  float rs  = rsqrtf(var + 1e-5f);
  bf16* orow = out + (size_t)row * E_DIM;
  orow[tid]       = __float2bfloat16((v0 - mu) * rs * g[tid]       + b[tid]);
  orow[tid + 256] = __float2bfloat16((v1 - mu) * rs * g[tid + 256] + b[tid + 256]);
  orow[tid + 512] = __float2bfloat16((v2 - mu) * rs * g[tid + 512] + b[tid + 512]);
}

// ---------------- V scatter: linear qkv -> vtb transposed layout -------------
// vtb[(((n*12+h)*128 + soct)*64 + d)*8 + slow] = qkv[(n*1024+s)*2304 + 1536 + h*64 + d]
__global__ __launch_bounds__(256) void scatter_v(const bf16* __restrict__ qkv,
                                                 bf16* __restrict__ vtb) {
  int blk = blockIdx.x;          // 1024 = n(8) x soct(128)
  int n = blk >> 7, soct = blk & 127;
  int tid = threadIdx.x;
  for (int j = tid; j < 768; j += 256) {
    int h = j >> 6, d = j & 63;
    const bf16* src = qkv + ((size_t)(n * 1024 + soct * 8)) * 2304 + 1536 + h * 64 + d;
    short8 v;
#pragma unroll
    for (int i = 0; i < 8; i++)
      v[i] = __builtin_bit_cast(short, src[(size_t)i * 2304]);
    *(short8*)&vtb[((((size_t)n * 12 + h) * 128 + soct) * 64 + d) * 8] = v;
  }
}

// ---------------- GEMM 256x256 8-phase, C = A @ Bt^T -------------------------
// 512 threads = 8 waves (2M x 4N), per-wave 128x64 output, BK=64, 2 K-tiles
// per iteration in 8 phases; counted vmcnt(6) at ph4/ph8 only. XOR swizzle
// on GLOBAL source, linear LDS dest (global_load_lds), reads XOR col group.
// MODE 1: linear bf16 + bias, cols<768 scaled 0.125 (qkv). MODE 2: gelu.
template <int MODE>
__global__ __launch_bounds__(512, 2) void gemm8(
    const bf16* __restrict__ A, const bf16* __restrict__ Bt,
    const float* __restrict__ bias, bf16* __restrict__ outb,
    int M, int N, int K) {
  __shared__ bf16 lA[2][16384];   // 2 x 32 KB (256 rows x 64)
  __shared__ bf16 lB[2][16384];   // 2 x 32 KB
  int tid = threadIdx.x;
  int w = tid >> 6, lane = tid & 63;
  int quad = lane >> 4, l16 = lane & 15;
  int wr = w >> 2, wc = w & 3;    // wave M-half (128 rows), N-quarter (64 cols)
  int gx = N >> 8;
  int flat = blockIdx.x;
  int y8 = flat & 7;
  int q2 = flat >> 3;
  int bx = q2 % gx;
  int by = (q2 / gx) * 8 + y8;
  int m0 = by << 8, n0 = bx << 8;

  f32x4 acc[8][4];
#pragma unroll
  for (int i = 0; i < 8; i++)
#pragma unroll
    for (int j = 0; j < 4; j++)
#pragma unroll
      for (int r = 0; r < 4; r++) acc[i][j][r] = 0.f;

  int xs = l16 & 7;                       // fragment-read XOR key (row&7)
  int ko0 = (quad ^ xs) << 3;             // ks=0 swizzled col offset (elems)
  int ko1 = ((4 + quad) ^ xs) << 3;       // ks=1
  int sgo = ((tid & 7) ^ ((tid >> 3) & 7)) << 3;  // staging src col (elems)
  size_t aRB = (size_t)(m0 + (tid >> 3)) * K + sgo;
  size_t bRB = (size_t)(n0 + ((tid >> 8) << 6) + ((tid >> 3) & 31)) * K + sgo;
  int aD = tid * 8;                       // A LDS dest base (elems)
  int bD = ((tid >> 8) << 12) + (tid & 255) * 8;  // B LDS dest base (elems)

  // Stage A quarter (mh): rows mh*64 + p*128 + [0,64)
  auto stA = [&](int buf, int mh, int kt) {
#pragma unroll
    for (int p = 0; p < 2; ++p)
      async_cp16(A + aRB + (size_t)(mh * 64 + p * 128) * K + (size_t)kt * 64,
                 &lA[buf][aD + mh * 4096 + p * 8192]);
  };
  // Stage B quarter (nh): rows nh*32 + p*128 + {0|64} + [0,32)
  auto stB = [&](int buf, int nh, int kt) {
#pragma unroll
    for (int p = 0; p < 2; ++p)
      async_cp16(Bt + bRB + (size_t)(nh * 32 + p * 128) * K + (size_t)kt * 64,
                 &lB[buf][bD + nh * 2048 + p * 8192]);
  };

  short8 af[4][2], b0f[2][2], b1f[2][2];

#define LD_A(BUF, MH)                                                      \
  {                                                                        \
    _Pragma("unroll") for (int i = 0; i < 4; ++i) {                        \
      const bf16* bp = &lA[BUF][(wr * 128 + (MH)*64 + i * 16 + l16) * 64]; \
      af[i][0] = *(const short8*)&bp[ko0];                                 \
      af[i][1] = *(const short8*)&bp[ko1];                                 \
    }                                                                      \
  }
#define LD_B(BUF, NH, DST)                                                 \
  {                                                                        \
    _Pragma("unroll") for (int j = 0; j < 2; ++j) {                        \
      const bf16* bp = &lB[BUF][(wc * 64 + (NH)*32 + j * 16 + l16) * 64];  \
      DST[j][0] = *(const short8*)&bp[ko0];                                \
      DST[j][1] = *(const short8*)&bp[ko1];                                \
    }                                                                      \
  }
#define DO_MFMA(MH, NH, BSRC)                                              \
  {                                                                        \
    __builtin_amdgcn_s_setprio(1);                                         \
    _Pragma("unroll") for (int ks = 0; ks < 2; ++ks)                       \
        _Pragma("unroll") for (int i = 0; i < 4; ++i)                      \
            _Pragma("unroll") for (int j = 0; j < 2; ++j)                  \
                acc[(MH)*4 + i][(NH)*2 + j] =                              \
        __builtin_amdgcn_mfma_f32_16x16x32_bf16(                           \
            BSRC[j][ks], af[i][ks], acc[(MH)*4 + i][(NH)*2 + j], 0, 0, 0); \
    __builtin_amdgcn_s_setprio(0);                                         \
  }
#define BAR() __builtin_amdgcn_s_barrier()
#define LGKM0() asm volatile("s_waitcnt lgkmcnt(0)" ::: "memory")
#define VM6() asm volatile("s_waitcnt vmcnt(6)" ::: "memory")
#define VM0() asm volatile("s_waitcnt vmcnt(0)" ::: "memory")

  // prologue: tile0 fully into buf0, tile1 quarters A0/B1/A1 into buf1
  stA(0, 0, 0); stA(0, 1, 0); stB(0, 0, 0); stB(0, 1, 0);
  stA(1, 0, 1); stB(1, 1, 1); stA(1, 1, 1);
  VM6();   // drains tile0's 8 loads (tile1's 6 stay in flight)
  BAR();

  int nit = K >> 7;   // 2 K-tiles per iteration (K % 128 == 0)
  for (int it = 0; it < nit; ++it) {
    int kt1 = 2 * it + 1, ktA = 2 * it + 2, ktB = 2 * it + 3;
    bool more = (it + 1 < nit);
    // ph1: quad(0,0) of buf0 | stage buf1.B-nh0 (tile kt1, last quarter)
    LD_A(0, 0); LD_B(0, 0, b0f);
    stB(1, 0, kt1);
    BAR(); LGKM0(); DO_MFMA(0, 0, b0f); BAR();
    // ph2: quad(0,1) | stage buf0.A-mh0 <- ktA
    LD_B(0, 1, b1f);
    if (more) stA(0, 0, ktA);
    BAR(); LGKM0(); DO_MFMA(0, 1, b1f); BAR();
    // ph3: quad(1,1) | stage buf0.B-nh1
    LD_A(0, 1);
    if (more) stB(0, 1, ktA);
    BAR(); LGKM0(); DO_MFMA(1, 1, b1f); BAR();
    // ph4: quad(1,0) | stage buf0.A-mh1; counted wait drains tile kt1's 8.
    LD_B(0, 0, b0f);
    if (more) { stA(0, 1, ktA); VM6(); } else { VM0(); }
    BAR(); LGKM0(); DO_MFMA(1, 0, b0f); BAR();
    // ph5: quad(0,0) of buf1 | stage buf0.B-nh0
    LD_A(1, 0); LD_B(1, 0, b0f);
    if (more) stB(0, 0, ktA);
    BAR(); LGKM0(); DO_MFMA(0, 0, b0f); BAR();
    // ph6: quad(0,1) | stage buf1.A-mh0 <- ktB
    LD_B(1, 1, b1f);
    if (more) stA(1, 0, ktB);
    BAR(); LGKM0(); DO_MFMA(0, 1, b1f); BAR();
    // ph7: quad(1,1) | stage buf1.B-nh1
    LD_A(1, 1);
    if (more) stB(1, 1, ktB);
    BAR(); LGKM0(); DO_MFMA(1, 1, b1f); BAR();
    // ph8: quad(1,0) | stage buf1.A-mh1; counted wait drains tile ktA's 8.
    LD_B(1, 0, b0f);
    if (more) { stA(1, 1, ktB); VM6(); }
    BAR(); LGKM0(); DO_MFMA(1, 0, b0f); BAR();
  }

#pragma unroll
  for (int nj = 0; nj < 4; ++nj) {
    int colb = n0 + wc * 64 + nj * 16 + quad * 4;   // 4 consecutive cols
    f32x4 b4 = *(const f32x4*)&bias[colb];
    float sc = (MODE == 1 && colb < 768) ? 0.125f : 1.0f;
#pragma unroll
    for (int mi = 0; mi < 8; ++mi) {
      int row = m0 + wr * 128 + mi * 16 + l16;
      f32x4 v = acc[mi][nj] + b4;
      short4v pk;
      if (MODE == 1) {
        for (int r = 0; r < 4; r++)
          pk[r] = __builtin_bit_cast(short, __float2bfloat16(v[r] * sc));
      } else {
        for (int r = 0; r < 4; r++) {
          float x = v[r];
          // tanh-form GELU: x * sigmoid(1.5957691*(x + 0.044715 x^3))
          float t = x * (1.59576912161f + 0.0713548162726f * x * x);
          float g = x * __builtin_amdgcn_rcpf(1.0f + __expf(-t));
          pk[r] = __builtin_bit_cast(short, __float2bfloat16(g));
        }
      }
      *(short4v*)&outb[(size_t)row * N + colb] = pk;
    }
  }
#undef LD_A
#undef LD_B
#undef DO_MFMA
#undef BAR
#undef LGKM0
#undef VM6
#undef VM0
}

// ---------------- GEMM 128x64: outf = A@Bt^T + bias + resid ------------------
__global__ __launch_bounds__(256) void gemm_bt64(
    const bf16* __restrict__ A, const bf16* __restrict__ Bt,
    const float* __restrict__ bias, const float* __restrict__ resid,
    float* __restrict__ outf, int M, int N, int K) {
  __shared__ bf16 As[2][128 * 64];   // 2 x 16 KB
  __shared__ bf16 Bs[2][64 * 64];    // 2 x  8 KB
  int tid = threadIdx.x;
  int wave = tid >> 6, lane = tid & 63;
  int quad = lane >> 4, l16 = lane & 15;
  int gx = N >> 6;                  // 12
  int flat = blockIdx.x;
  int y8 = flat & 7;
  int q2 = flat >> 3;
  int bx = q2 % gx;
  int by = (q2 / gx) * 8 + y8;
  int m0 = by * 128, n0 = bx * 64;
  int wm = wave * 32;               // wave owns 32 M-rows, all 64 N-cols
  f32x4 acc[2][4];
  for (int i = 0; i < 2; i++)
    for (int j = 0; j < 4; j++)
      for (int r = 0; r < 4; r++) acc[i][j][r] = 0.f;

  int xs = l16 & 7;
  int srow = tid >> 3;
  int scg = (((tid & 7) ^ (srow & 7)) << 3);
  const bf16* aptr = A  + (size_t)(m0 + srow) * K + scg;
  const bf16* bptr = Bt + (size_t)(n0 + srow) * K + scg;
  int ldst = tid * 8;

#pragma unroll
  for (int t = 0; t < 4; t++)
    async_cp16(aptr + (size_t)t * 32 * K, &As[0][ldst + t * 2048]);
#pragma unroll
  for (int t = 0; t < 2; t++)
    async_cp16(bptr + (size_t)t * 32 * K, &Bs[0][ldst + t * 2048]);

  int nkb = K >> 6;
  for (int ik = 0; ik < nkb; ++ik) {
    int cur = ik & 1;
    if (ik + 1 < nkb) {
      size_t ko = (size_t)(ik + 1) * 64;
#pragma unroll
      for (int t = 0; t < 4; t++)
        async_cp16(aptr + ko + (size_t)t * 32 * K, &As[cur ^ 1][ldst + t * 2048]);
#pragma unroll
      for (int t = 0; t < 2; t++)
        async_cp16(bptr + ko + (size_t)t * 32 * K, &Bs[cur ^ 1][ldst + t * 2048]);
      asm volatile("s_waitcnt vmcnt(6)" ::: "memory");
    } else {
      asm volatile("s_waitcnt vmcnt(0)" ::: "memory");
    }
    __builtin_amdgcn_s_barrier();
    asm volatile("" ::: "memory");
#pragma unroll
    for (int ks = 0; ks < 2; ks++) {
      int ko2 = (((ks * 4 + quad) ^ xs) << 3);
      short8 af[2], bfr[4];
      for (int i = 0; i < 2; i++)
        af[i] = *(const short8*)&As[cur][(wm + i * 16 + l16) * 64 + ko2];
      for (int j = 0; j < 4; j++)
        bfr[j] = *(const short8*)&Bs[cur][(j * 16 + l16) * 64 + ko2];
      for (int i = 0; i < 2; i++)
        for (int j = 0; j < 4; j++)
          acc[i][j] = __builtin_amdgcn_mfma_f32_16x16x32_bf16(
              bfr[j], af[i], acc[i][j], 0, 0, 0);
    }
    asm volatile("" ::: "memory");
    __builtin_amdgcn_s_barrier();
  }

  for (int j = 0; j < 4; j++) {
    int colb = n0 + j * 16 + quad * 4;
    f32x4 b4 = *(const f32x4*)&bias[colb];
    for (int i = 0; i < 2; i++) {
      int row = m0 + wm + i * 16 + l16;
      size_t idx = (size_t)row * N + colb;
      f32x4 rv = *(const f32x4*)&resid[idx];
      *(f32x4*)&outf[idx] = acc[i][j] + b4 + rv;
    }
  }
}

// ---------------- flash attention: paired q-tiles, pipelined K/V -------------
// Q and K read directly from linear qkv [8192 x 2304] (Q pre-scaled 0.125);
// V from vtb transposed layout. K staging: per-(row,head) 128B line fully
// consumed by the 8 c-octet global_load_lds ops; heads pinned per-XCD.
__global__ __launch_bounds__(256) void attn_fwd(
    const bf16* __restrict__ qkv, const bf16* __restrict__ vg,
    bf16* __restrict__ out) {
  __shared__ bf16 kt2[2][8 * 64 * 8];  // 16 KB
  __shared__ bf16 vt2[2][8 * 64 * 8];  // 16 KB
  __shared__ bf16 pba[4][16 * 68];     // per-wave P, tile a (8.5 KB)
  __shared__ bf16 pbb[4][16 * 68];     // per-wave P, tile b (8.5 KB)
  int flat = blockIdx.x;             // 768 blocks
  int xcd = flat & 7;
  int j = flat >> 3;                 // 0..95
  int a = j & 7;                     // low q-tile 0..7
  int g = j >> 3;                    // 0..11
  int nh = xcd * 12 + g;             // head: all its blocks share flat&7
  int b = 15 - a;                    // high q-tile 8..15
  int n = nh / H_N, h = nh % H_N;
  int tid = threadIdx.x, wave = tid >> 6, lane = tid & 63;
  int quad = lane >> 4, l16 = lane & 15;
  const bf16* qp = qkv + (size_t)n * S_LEN * 2304 + (size_t)h * 64;
  const bf16* vp = vg + (size_t)nh * 128 * 64 * 8;
  int qra = a * 64 + wave * 16;      // tile-a wave rows; lane's q = qra + l16
  int qrb = b * 64 + wave * 16;

  short8 qfa[2], qfb[2];
  qfa[0] = *(const short8*)&qp[(size_t)(qra + l16) * 2304 + quad * 8];
  qfa[1] = *(const short8*)&qp[(size_t)(qra + l16) * 2304 + 32 + quad * 8];
  qfb[0] = *(const short8*)&qp[(size_t)(qrb + l16) * 2304 + quad * 8];
  qfb[1] = *(const short8*)&qp[(size_t)(qrb + l16) * 2304 + 32 + quad * 8];

  // K staging: slot = t*256+tid -> c-octet = t*4+(tid>>6), krow = tid&63
  const bf16* kbase = qkv + ((size_t)n * S_LEN + (tid & 63)) * 2304 + 768 +
                      h * 64 + ((tid >> 6) << 3);
  const bf16* vbase = vp + (((size_t)(tid >> 6) * 64) + (tid & 63)) * 8;

  f32x4 oaa[4], oab[4];              // O^T: d = dt*16+quad*4+r, q = l16
  for (int dt = 0; dt < 4; dt++)
    for (int r = 0; r < 4; r++) { oaa[dt][r] = 0.f; oab[dt][r] = 0.f; }
  float lia = 0.f, lib = 0.f;

  {
    bf16* lk = &kt2[0][0] + tid * 8;
    bf16* lv = &vt2[0][0] + tid * 8;
#pragma unroll
    for (int t = 0; t < 2; ++t) {
      async_cp16(kbase + t * 32, lk + t * 2048);
      async_cp16(vbase + (size_t)t * 2048, lv + t * 2048);
    }
  }

  for (int kb = 0; kb <= b; ++kb) {
    bool act_a = (kb <= a);
    int cur = kb & 1;
    __syncthreads();   // drains prefetch issued last iteration

    short8 kf[2][4], vf[2][4];
#pragma unroll
    for (int ks = 0; ks < 2; ks++)
      for (int nt = 0; nt < 4; nt++) {
        kf[ks][nt] = *(const short8*)
            &kt2[cur][(size_t)((ks * 4 + quad) * 64 + nt * 16 + l16) * 8];
        vf[ks][nt] = *(const short8*)
            &vt2[cur][(size_t)((ks * 4 + quad) * 64 + nt * 16 + l16) * 8];
      }
    if (kb < b) {
      bf16* lk = &kt2[cur ^ 1][0] + tid * 8;
      bf16* lv = &vt2[cur ^ 1][0] + tid * 8;
      size_t kko = (size_t)(kb + 1) * 64 * 2304;  // next 64 k-rows
      size_t vko = (size_t)(kb + 1) * 4096;
#pragma unroll
      for (int t = 0; t < 2; ++t) {
        async_cp16(kbase + kko + t * 32, lk + t * 2048);
        async_cp16(vbase + vko + (size_t)t * 2048, lv + t * 2048);
      }
    }

    f32x4 sb4[4], sa4[4];
    for (int nt = 0; nt < 4; nt++) {
      for (int r = 0; r < 4; r++) { sb4[nt][r] = -10.f; sa4[nt][r] = -10.f; }
      for (int ks = 0; ks < 2; ks++) {
        sb4[nt] = __builtin_amdgcn_mfma_f32_16x16x32_bf16(kf[ks][nt], qfb[ks],
                                                          sb4[nt], 0, 0, 0);
        if (act_a)
          sa4[nt] = __builtin_amdgcn_mfma_f32_16x16x32_bf16(kf[ks][nt], qfa[ks],
                                                            sa4[nt], 0, 0, 0);
      }
    }
    if (kb == b) {
      int ql = wave * 16 + l16;
      for (int nt = 0; nt < 4; nt++)
        for (int r = 0; r < 4; r++)
          if (nt * 16 + quad * 4 + r > ql) sb4[nt][r] = -INFINITY;
    }
    if (kb == a) {
      int ql = wave * 16 + l16;
      for (int nt = 0; nt < 4; nt++)
        for (int r = 0; r < 4; r++)
          if (nt * 16 + quad * 4 + r > ql) sa4[nt][r] = -INFINITY;
    }

    float rsb = 0.f;
    for (int nt = 0; nt < 4; nt++)
      for (int r = 0; r < 4; r++) {
        float p = __expf(sb4[nt][r]);
        sb4[nt][r] = p;
        rsb += p;
      }
    rsb += __shfl_xor(rsb, 16);
    rsb += __shfl_xor(rsb, 32);
    lib += rsb;
    bf16* pwb = pbb[wave];
    for (int nt = 0; nt < 4; nt++) {
      short4v pk;
      for (int r = 0; r < 4; r++)
        pk[r] = __builtin_bit_cast(short, __float2bfloat16(sb4[nt][r]));
      *(short4v*)&pwb[l16 * 68 + nt * 16 + quad * 4] = pk;
    }
    if (act_a) {
      float rsa = 0.f;
      for (int nt = 0; nt < 4; nt++)
        for (int r = 0; r < 4; r++) {
          float p = __expf(sa4[nt][r]);
          sa4[nt][r] = p;
          rsa += p;
        }
      rsa += __shfl_xor(rsa, 16);
      rsa += __shfl_xor(rsa, 32);
      lia += rsa;
      bf16* pwa = pba[wave];
      for (int nt = 0; nt < 4; nt++) {
        short4v pk;
        for (int r = 0; r < 4; r++)
          pk[r] = __builtin_bit_cast(short, __float2bfloat16(sa4[nt][r]));
        *(short4v*)&pwa[l16 * 68 + nt * 16 + quad * 4] = pk;
      }
    }
    asm volatile("s_waitcnt lgkmcnt(0)" ::: "memory");  // same-wave LDS RAW

    for (int ks = 0; ks < 2; ks++) {
      short8 pfb = *(const short8*)&pbb[wave][l16 * 68 + ks * 32 + quad * 8];
      short8 pfa;
      if (act_a) pfa = *(const short8*)&pba[wave][l16 * 68 + ks * 32 + quad * 8];
      for (int dt = 0; dt < 4; dt++) {
        oab[dt] = __builtin_amdgcn_mfma_f32_16x16x32_bf16(vf[ks][dt], pfb,
                                                          oab[dt], 0, 0, 0);
        if (act_a)
          oaa[dt] = __builtin_amdgcn_mfma_f32_16x16x32_bf16(vf[ks][dt], pfa,
                                                            oaa[dt], 0, 0, 0);
      }
    }
  }

  float inva = 1.0f / lia, invb = 1.0f / lib;
  int ta = n * S_LEN + qra + l16;
  int tb = n * S_LEN + qrb + l16;
  for (int dt = 0; dt < 4; dt++) {
    short4v ova, ovb;
    for (int r = 0; r < 4; r++) {
      ova[r] = __builtin_bit_cast(short, __float2bfloat16(oaa[dt][r] * inva));
      ovb[r] = __builtin_bit_cast(short, __float2bfloat16(oab[dt][r] * invb));
    }
    *(short4v*)&out[(size_t)ta * E_DIM + h * 64 + dt * 16 + quad * 4] = ova;
    *(short4v*)&out[(size_t)tb * E_DIM + h * 64 + dt * 16 + quad * 4] = ovb;
  }
}

extern "C" void kernel_launch(void* const* d_in, const int* in_sizes, int n_in,
                              void* d_out, int out_size, void* d_ws, size_t ws_size,
                              hipStream_t stream) {
  (void)in_sizes; (void)n_in; (void)out_size; (void)ws_size;
  const float* x      = (const float*)d_in[0];
  const float* ln1_g  = (const float*)d_in[1];
  const float* ln1_b  = (const float*)d_in[2];
  const float* ln2_g  = (const float*)d_in[3];
  const float* ln2_b  = (const float*)d_in[4];
  const float* w_attn = (const float*)d_in[5];
  const float* b_attn = (const float*)d_in[6];
  const float* w_proj = (const float*)d_in[7];
  const float* b_proj = (const float*)d_in[8];
  const float* w_fc   = (const float*)d_in[9];
  const float* b_fc   = (const float*)d_in[10];
  const float* w_fc2  = (const float*)d_in[11];
  const float* b_fc2  = (const float*)d_in[12];
  float* out = (float*)d_out;

  char* ws = (char*)d_ws;
  bf16* wt_attn = (bf16*)(ws);                 //  3,538,944 B
  bf16* wt_proj = (bf16*)(ws + 3538944);       //  1,179,648 B
  bf16* wt_fc   = (bf16*)(ws + 4718592);       //  4,718,592 B
  bf16* wt_fc2  = (bf16*)(ws + 9437184);       //  4,718,592 B
  bf16* hbuf    = (bf16*)(ws + 14155776);      // 12,582,912 B (also ao)
  float* x2     = (float*)(ws + 26738688);     // 25,165,824 B
  bf16* qkvb    = (bf16*)(ws + 51904512);      // 37,748,736 B (linear qkv)
  bf16* vtb     = (bf16*)(ws + 89653248);      // 12,582,912 B (ends 102,236,160)
  bf16* ao      = hbuf;                        // alias: hbuf dead after QKV gemm
  bf16* ff      = qkvb;  // reuse qkv+vtb region (50,331,648 B needed)

  dim3 blk(256);
  wcastT_all<<<dim3(6912), blk, 0, stream>>>(w_attn, w_proj, w_fc, w_fc2,
                                             wt_attn, wt_proj, wt_fc, wt_fc2);

  ln_rows<<<8192, blk, 0, stream>>>(x, ln1_g, ln1_b, hbuf);

  // QKV: M=8192, N=2304, K=768 -> 288 blocks of 512; linear output, q scaled
  gemm8<1><<<dim3(288), dim3(512), 0, stream>>>(
      hbuf, wt_attn, b_attn, qkvb, 8192, 2304, 768);

  scatter_v<<<dim3(1024), blk, 0, stream>>>(qkvb, vtb);

  attn_fwd<<<dim3(768), blk, 0, stream>>>(qkvb, vtb, ao);

  gemm_bt64<<<dim3(12 * 64), blk, 0, stream>>>(
      ao, wt_proj, b_proj, x, x2, 8192, 768, 768);

  ln_rows<<<8192, blk, 0, stream>>>(x2, ln2_g, ln2_b, hbuf);

  // FC1: M=8192, N=3072, K=768 -> 384 blocks
  gemm8<2><<<dim3(384), dim3(512), 0, stream>>>(
      hbuf, wt_fc, b_fc, ff, 8192, 3072, 768);

  gemm_bt64<<<dim3(12 * 64), blk, 0, stream>>>(
      ff, wt_fc2, b_fc2, x2, out, 8192, 768, 3072);
}

// Round 4
// 360.640 us; speedup vs baseline: 1.0502x; 1.0502x over previous
//
#include <hip/hip_runtime.h>
#include <hip/hip_bf16.h>
#include <stdint.h>

#define S_LEN 1024
#define E_DIM 768
#define H_N   12
#define FF_DIM 3072

typedef __hip_bfloat16 bf16;
using short8  = __attribute__((ext_vector_type(8))) short;
using short4v = __attribute__((ext_vector_type(4))) short;
using f32x4   = __attribute__((ext_vector_type(4))) float;

__device__ __forceinline__ void async_cp16(const void* g, void* l) {
  __builtin_amdgcn_global_load_lds(
      (__attribute__((address_space(1))) void*)(g),
      (__attribute__((address_space(3))) void*)(l), 16, 0, 0);
}

// -------- fused weight transpose + cast (all 4 weights, one launch) ----------
__global__ __launch_bounds__(256) void wcastT_all(
    const float* __restrict__ wa, const float* __restrict__ wp,
    const float* __restrict__ wf, const float* __restrict__ wf2,
    bf16* __restrict__ oa, bf16* __restrict__ op,
    bf16* __restrict__ of, bf16* __restrict__ of2) {
  __shared__ float t[32][33];
  int bid = blockIdx.x;
  const float* w; bf16* wt; int K, N, bx, by;
  if (bid < 1728)      { w = wa;  wt = oa;  K = 768;  N = 2304; int r = bid;        bx = r % 72; by = r / 72; }
  else if (bid < 2304) { w = wp;  wt = op;  K = 768;  N = 768;  int r = bid - 1728; bx = r % 24; by = r / 24; }
  else if (bid < 4608) { w = wf;  wt = of;  K = 768;  N = 3072; int r = bid - 2304; bx = r % 96; by = r / 96; }
  else                 { w = wf2; wt = of2; K = 3072; N = 768;  int r = bid - 4608; bx = r % 24; by = r / 24; }
  int x = threadIdx.x & 31;
  int y = threadIdx.x >> 5;     // 0..7
  for (int i = y; i < 32; i += 8)
    t[i][x] = w[(size_t)(by * 32 + i) * N + bx * 32 + x];
  __syncthreads();
  for (int i = y; i < 32; i += 8)
    wt[(size_t)(bx * 32 + i) * K + by * 32 + x] = __float2bfloat16(t[x][i]);
}

// ---------------- layernorm over E=768, out bf16 -----------------------------
__global__ __launch_bounds__(256) void ln_rows(const float* __restrict__ x,
                                               const float* __restrict__ g,
                                               const float* __restrict__ b,
                                               bf16* __restrict__ out) {
  int row = blockIdx.x;
  int tid = threadIdx.x;
  const float* xr = x + (size_t)row * E_DIM;
  float v0 = xr[tid], v1 = xr[tid + 256], v2 = xr[tid + 512];
  float s = v0 + v1 + v2;
  float ss = v0 * v0 + v1 * v1 + v2 * v2;
  for (int o = 32; o > 0; o >>= 1) {
    s  += __shfl_down(s, o);
    ss += __shfl_down(ss, o);
  }
  __shared__ float ps[4], pq[4];
  int wv = tid >> 6;
  if ((tid & 63) == 0) { ps[wv] = s; pq[wv] = ss; }
  __syncthreads();
  s  = ps[0] + ps[1] + ps[2] + ps[3];
  ss = pq[0] + pq[1] + pq[2] + pq[3];
  float mu  = s * (1.0f / E_DIM);
  float var = ss * (1.0f / E_DIM) - mu * mu;
  float rs  = rsqrtf(var + 1e-5f);
  bf16* orow = out + (size_t)row * E_DIM;
  orow[tid]       = __float2bfloat16((v0 - mu) * rs * g[tid]       + b[tid]);
  orow[tid + 256] = __float2bfloat16((v1 - mu) * rs * g[tid + 256] + b[tid + 256]);
  orow[tid + 512] = __float2bfloat16((v2 - mu) * rs * g[tid + 512] + b[tid + 512]);
}

// ---------------- V scatter: linear qkv -> vtb transposed layout -------------
__global__ __launch_bounds__(256) void scatter_v(const bf16* __restrict__ qkv,
                                                 bf16* __restrict__ vtb) {
  int blk = blockIdx.x;          // 1024 = n(8) x soct(128)
  int n = blk >> 7, soct = blk & 127;
  int tid = threadIdx.x;
  for (int j = tid; j < 768; j += 256) {
    int h = j >> 6, d = j & 63;
    const bf16* src = qkv + ((size_t)(n * 1024 + soct * 8)) * 2304 + 1536 + h * 64 + d;
    short8 v;
#pragma unroll
    for (int i = 0; i < 8; i++)
      v[i] = __builtin_bit_cast(short, src[(size_t)i * 2304]);
    *(short8*)&vtb[((((size_t)n * 12 + h) * 128 + soct) * 64 + d) * 8] = v;
  }
}

// ---------------- GEMM 256x128 4-phase 8-wave, C = A @ Bt^T ------------------
// 512 threads = 8 waves (2M x 4N), per-wave 128x32 output (acc = 64 f32/lane,
// ~half the 256x256 version's register state -> no spill at the 256-reg cap).
// BK=64, 2 K-tiles/iter in 4 phases of 16 MFMA each; counted vmcnt(4) twice
// per iter, never 0 in steady state. XOR swizzle on GLOBAL source, linear
// LDS dest (global_load_lds); reads XOR the column group. A staged per
// 64-row stripe-pair matching phase consumption (region free exactly one
// phase before its restage); B fragments persist in regs across ph-pairs so
// B region frees after its first phase. LDS 96 KB.
// MODE 1: linear bf16 + bias, cols<768 scaled 0.125 (qkv). MODE 2: gelu.
template <int MODE>
__global__ __launch_bounds__(512, 2) void gemm8(
    const bf16* __restrict__ A, const bf16* __restrict__ Bt,
    const float* __restrict__ bias, bf16* __restrict__ outb,
    int M, int N, int K) {
  __shared__ bf16 lA[2][16384];   // 2 x 32 KB: elem = mh*4096 + p*8192 + r64*64 + c
  __shared__ bf16 lB[2][8192];    // 2 x 16 KB: elem = p*4096 + r64*64 + c
  int tid = threadIdx.x;
  int w = tid >> 6, lane = tid & 63;
  int quad = lane >> 4, l16 = lane & 15;
  int wr = w >> 2, wc = w & 3;    // wave rows wr*128..+128, cols wc*32..+32
  int gx = N >> 7;
  int flat = blockIdx.x;
  int y8 = flat & 7;
  int q2 = flat >> 3;
  int bx = q2 % gx;
  int by = (q2 / gx) * 8 + y8;
  int m0 = by << 8, n0 = bx << 7;

  f32x4 acc[8][2];
#pragma unroll
  for (int i = 0; i < 8; i++)
#pragma unroll
    for (int j = 0; j < 2; j++)
#pragma unroll
      for (int r = 0; r < 4; r++) acc[i][j][r] = 0.f;

  int xs = l16 & 7;                       // fragment-read XOR key (row&7)
  int ko0 = (quad ^ xs) << 3;             // ks=0 swizzled col offset (elems)
  int ko1 = ((4 + quad) ^ xs) << 3;       // ks=1
  int sgo = ((tid & 7) ^ ((tid >> 3) & 7)) << 3;  // staging src col (elems)
  size_t aRB = (size_t)(m0 + (tid >> 3)) * K + sgo;
  size_t bRB = (size_t)(n0 + (tid >> 3)) * K + sgo;
  int aD = tid * 8;                       // A LDS dest base (elems)
  int bD = tid * 8;                       // B LDS dest base (elems)

  // Stage A stripe-pair mh: global rows {m0 + p*128 + mh*64 + [0,64)}, p=0,1
  auto stA = [&](int buf, int mh, int kt) {
#pragma unroll
    for (int p = 0; p < 2; ++p)
      async_cp16(A + aRB + (size_t)(p * 128 + mh * 64) * K + (size_t)kt * 64,
                 &lA[buf][aD + mh * 4096 + p * 8192]);
  };
  // Stage whole B tile: rows n0 + p*64 + [0,64)
  auto stB = [&](int buf, int kt) {
#pragma unroll
    for (int p = 0; p < 2; ++p)
      async_cp16(Bt + bRB + (size_t)(p * 64) * K + (size_t)kt * 64,
                 &lB[buf][bD + p * 4096]);
  };

  short8 af[4][2], bf[2][2];

#define LD_A(BUF, MH)                                                        \
  {                                                                          \
    _Pragma("unroll") for (int i = 0; i < 4; ++i) {                          \
      const bf16* bp =                                                       \
          &lA[BUF][(MH)*4096 + wr * 8192 + (i * 16 + l16) * 64];             \
      af[i][0] = *(const short8*)&bp[ko0];                                   \
      af[i][1] = *(const short8*)&bp[ko1];                                   \
    }                                                                        \
  }
#define LD_B(BUF)                                                            \
  {                                                                          \
    _Pragma("unroll") for (int j = 0; j < 2; ++j) {                          \
      int rb = wc * 32 + j * 16 + l16;                                       \
      const bf16* bp = &lB[BUF][((rb >> 6) << 12) + ((rb & 63) << 6)];       \
      bf[j][0] = *(const short8*)&bp[ko0];                                   \
      bf[j][1] = *(const short8*)&bp[ko1];                                   \
    }                                                                        \
  }
#define DO_MFMA(MH)                                                          \
  {                                                                          \
    __builtin_amdgcn_s_setprio(1);                                           \
    _Pragma("unroll") for (int ks = 0; ks < 2; ++ks)                         \
        _Pragma("unroll") for (int i = 0; i < 4; ++i)                        \
            _Pragma("unroll") for (int j = 0; j < 2; ++j)                    \
                acc[(MH)*4 + i][j] =                                         \
        __builtin_amdgcn_mfma_f32_16x16x32_bf16(                             \
            bf[j][ks], af[i][ks], acc[(MH)*4 + i][j], 0, 0, 0);              \
    __builtin_amdgcn_s_setprio(0);                                           \
  }
#define BAR() __builtin_amdgcn_s_barrier()
#define LGKM0() asm volatile("s_waitcnt lgkmcnt(0)" ::: "memory")
#define VM4() asm volatile("s_waitcnt vmcnt(4)" ::: "memory")
#define VM0() asm volatile("s_waitcnt vmcnt(0)" ::: "memory")

  // prologue: buf0 = tile0 full (6 ops); buf1 = tile1 {A-mh0, B} (4 ops)
  stA(0, 0, 0); stA(0, 1, 0); stB(0, 0);
  stA(1, 0, 1); stB(1, 1);
  VM4();   // drains buf0's 6; buf1's 4 stay in flight
  BAR();

  int nit = K >> 7;   // 2 K-tiles per iteration (K % 128 == 0)
  for (int it = 0; it < nit; ++it) {
    int ktA = 2 * it + 2, ktB = 2 * it + 3;
    bool more = (it + 1 < nit);
    // ph1: buf0.mh0 | stage buf1.A-mh1 (current tile 2it+1, last piece)
    LD_A(0, 0); LD_B(0);
    stA(1, 1, 2 * it + 1);
    BAR(); LGKM0(); DO_MFMA(0); BAR();
    // ph2: buf0.mh1 (bf kept) | stage buf0.{A-mh0,B} <- ktA; drain to 4:
    // keeps only ph2's own ops; buf1 tile (prev-ph4 + ph1 stages) landed.
    LD_A(0, 1);
    if (more) { stA(0, 0, ktA); stB(0, ktA); VM4(); } else { VM0(); }
    BAR(); LGKM0(); DO_MFMA(1); BAR();
    // ph3: buf1.mh0 | stage buf0.A-mh1 <- ktA
    LD_A(1, 0); LD_B(1);
    if (more) stA(0, 1, ktA);
    BAR(); LGKM0(); DO_MFMA(0); BAR();
    // ph4: buf1.mh1 (bf kept) | stage buf1.{A-mh0,B} <- ktB; drain to 4:
    // keeps only ph4's own ops; buf0 tile ktA (ph2+ph3 stages) landed.
    LD_A(1, 1);
    if (more) { stA(1, 0, ktB); stB(1, ktB); VM4(); }
    BAR(); LGKM0(); DO_MFMA(1); BAR();
  }

#pragma unroll
  for (int nj = 0; nj < 2; ++nj) {
    int colb = n0 + wc * 32 + nj * 16 + quad * 4;   // 4 consecutive cols
    f32x4 b4 = *(const f32x4*)&bias[colb];
    float sc = (MODE == 1 && colb < 768) ? 0.125f : 1.0f;
#pragma unroll
    for (int mi = 0; mi < 8; ++mi) {
      int row = m0 + wr * 128 + mi * 16 + l16;
      f32x4 v = acc[mi][nj] + b4;
      short4v pk;
      if (MODE == 1) {
        for (int r = 0; r < 4; r++)
          pk[r] = __builtin_bit_cast(short, __float2bfloat16(v[r] * sc));
      } else {
        for (int r = 0; r < 4; r++) {
          float x = v[r];
          // tanh-form GELU: x * sigmoid(1.5957691*(x + 0.044715 x^3))
          float t = x * (1.59576912161f + 0.0713548162726f * x * x);
          float g = x * __builtin_amdgcn_rcpf(1.0f + __expf(-t));
          pk[r] = __builtin_bit_cast(short, __float2bfloat16(g));
        }
      }
      *(short4v*)&outb[(size_t)row * N + colb] = pk;
    }
  }
#undef LD_A
#undef LD_B
#undef DO_MFMA
#undef BAR
#undef LGKM0
#undef VM4
#undef VM0
}

// ---------------- GEMM 128x64: outf = A@Bt^T + bias + resid ------------------
__global__ __launch_bounds__(256) void gemm_bt64(
    const bf16* __restrict__ A, const bf16* __restrict__ Bt,
    const float* __restrict__ bias, const float* __restrict__ resid,
    float* __restrict__ outf, int M, int N, int K) {
  __shared__ bf16 As[2][128 * 64];   // 2 x 16 KB
  __shared__ bf16 Bs[2][64 * 64];    // 2 x  8 KB
  int tid = threadIdx.x;
  int wave = tid >> 6, lane = tid & 63;
  int quad = lane >> 4, l16 = lane & 15;
  int gx = N >> 6;                  // 12
  int flat = blockIdx.x;
  int y8 = flat & 7;
  int q2 = flat >> 3;
  int bx = q2 % gx;
  int by = (q2 / gx) * 8 + y8;
  int m0 = by * 128, n0 = bx * 64;
  int wm = wave * 32;               // wave owns 32 M-rows, all 64 N-cols
  f32x4 acc[2][4];
  for (int i = 0; i < 2; i++)
    for (int j = 0; j < 4; j++)
      for (int r = 0; r < 4; r++) acc[i][j][r] = 0.f;

  int xs = l16 & 7;
  int srow = tid >> 3;
  int scg = (((tid & 7) ^ (srow & 7)) << 3);
  const bf16* aptr = A  + (size_t)(m0 + srow) * K + scg;
  const bf16* bptr = Bt + (size_t)(n0 + srow) * K + scg;
  int ldst = tid * 8;

#pragma unroll
  for (int t = 0; t < 4; t++)
    async_cp16(aptr + (size_t)t * 32 * K, &As[0][ldst + t * 2048]);
#pragma unroll
  for (int t = 0; t < 2; t++)
    async_cp16(bptr + (size_t)t * 32 * K, &Bs[0][ldst + t * 2048]);

  int nkb = K >> 6;
  for (int ik = 0; ik < nkb; ++ik) {
    int cur = ik & 1;
    if (ik + 1 < nkb) {
      size_t ko = (size_t)(ik + 1) * 64;
#pragma unroll
      for (int t = 0; t < 4; t++)
        async_cp16(aptr + ko + (size_t)t * 32 * K, &As[cur ^ 1][ldst + t * 2048]);
#pragma unroll
      for (int t = 0; t < 2; t++)
        async_cp16(bptr + ko + (size_t)t * 32 * K, &Bs[cur ^ 1][ldst + t * 2048]);
      asm volatile("s_waitcnt vmcnt(6)" ::: "memory");
    } else {
      asm volatile("s_waitcnt vmcnt(0)" ::: "memory");
    }
    __builtin_amdgcn_s_barrier();
    asm volatile("" ::: "memory");
#pragma unroll
    for (int ks = 0; ks < 2; ks++) {
      int ko2 = (((ks * 4 + quad) ^ xs) << 3);
      short8 af[2], bfr[4];
      for (int i = 0; i < 2; i++)
        af[i] = *(const short8*)&As[cur][(wm + i * 16 + l16) * 64 + ko2];
      for (int j = 0; j < 4; j++)
        bfr[j] = *(const short8*)&Bs[cur][(j * 16 + l16) * 64 + ko2];
      for (int i = 0; i < 2; i++)
        for (int j = 0; j < 4; j++)
          acc[i][j] = __builtin_amdgcn_mfma_f32_16x16x32_bf16(
              bfr[j], af[i], acc[i][j], 0, 0, 0);
    }
    asm volatile("" ::: "memory");
    __builtin_amdgcn_s_barrier();
  }

  for (int j = 0; j < 4; j++) {
    int colb = n0 + j * 16 + quad * 4;
    f32x4 b4 = *(const f32x4*)&bias[colb];
    for (int i = 0; i < 2; i++) {
      int row = m0 + wm + i * 16 + l16;
      size_t idx = (size_t)row * N + colb;
      f32x4 rv = *(const f32x4*)&resid[idx];
      *(f32x4*)&outf[idx] = acc[i][j] + b4 + rv;
    }
  }
}

// ---------------- flash attention: paired q-tiles, pipelined K/V -------------
// Q and K read directly from linear qkv [8192 x 2304] (Q pre-scaled 0.125);
// V from vtb transposed layout.
__global__ __launch_bounds__(256) void attn_fwd(
    const bf16* __restrict__ qkv, const bf16* __restrict__ vg,
    bf16* __restrict__ out) {
  __shared__ bf16 kt2[2][8 * 64 * 8];  // 16 KB
  __shared__ bf16 vt2[2][8 * 64 * 8];  // 16 KB
  __shared__ bf16 pba[4][16 * 68];     // per-wave P, tile a (8.5 KB)
  __shared__ bf16 pbb[4][16 * 68];     // per-wave P, tile b (8.5 KB)
  int flat = blockIdx.x;             // 768 blocks
  int xcd = flat & 7;
  int j = flat >> 3;                 // 0..95
  int a = j & 7;                     // low q-tile 0..7
  int g = j >> 3;                    // 0..11
  int nh = xcd * 12 + g;             // head: all its blocks share flat&7
  int b = 15 - a;                    // high q-tile 8..15
  int n = nh / H_N, h = nh % H_N;
  int tid = threadIdx.x, wave = tid >> 6, lane = tid & 63;
  int quad = lane >> 4, l16 = lane & 15;
  const bf16* qp = qkv + (size_t)n * S_LEN * 2304 + (size_t)h * 64;
  const bf16* vp = vg + (size_t)nh * 128 * 64 * 8;
  int qra = a * 64 + wave * 16;      // tile-a wave rows; lane's q = qra + l16
  int qrb = b * 64 + wave * 16;

  short8 qfa[2], qfb[2];
  qfa[0] = *(const short8*)&qp[(size_t)(qra + l16) * 2304 + quad * 8];
  qfa[1] = *(const short8*)&qp[(size_t)(qra + l16) * 2304 + 32 + quad * 8];
  qfb[0] = *(const short8*)&qp[(size_t)(qrb + l16) * 2304 + quad * 8];
  qfb[1] = *(const short8*)&qp[(size_t)(qrb + l16) * 2304 + 32 + quad * 8];

  // K staging: slot = t*256+tid -> c-octet = t*4+(tid>>6), krow = tid&63
  const bf16* kbase = qkv + ((size_t)n * S_LEN + (tid & 63)) * 2304 + 768 +
                      h * 64 + ((tid >> 6) << 3);
  const bf16* vbase = vp + (((size_t)(tid >> 6) * 64) + (tid & 63)) * 8;

  f32x4 oaa[4], oab[4];              // O^T: d = dt*16+quad*4+r, q = l16
  for (int dt = 0; dt < 4; dt++)
    for (int r = 0; r < 4; r++) { oaa[dt][r] = 0.f; oab[dt][r] = 0.f; }
  float lia = 0.f, lib = 0.f;

  {
    bf16* lk = &kt2[0][0] + tid * 8;
    bf16* lv = &vt2[0][0] + tid * 8;
#pragma unroll
    for (int t = 0; t < 2; ++t) {
      async_cp16(kbase + t * 32, lk + t * 2048);
      async_cp16(vbase + (size_t)t * 2048, lv + t * 2048);
    }
  }

  for (int kb = 0; kb <= b; ++kb) {
    bool act_a = (kb <= a);
    int cur = kb & 1;
    __syncthreads();   // drains prefetch issued last iteration

    short8 kf[2][4], vf[2][4];
#pragma unroll
    for (int ks = 0; ks < 2; ks++)
      for (int nt = 0; nt < 4; nt++) {
        kf[ks][nt] = *(const short8*)
            &kt2[cur][(size_t)((ks * 4 + quad) * 64 + nt * 16 + l16) * 8];
        vf[ks][nt] = *(const short8*)
            &vt2[cur][(size_t)((ks * 4 + quad) * 64 + nt * 16 + l16) * 8];
      }
    if (kb < b) {
      bf16* lk = &kt2[cur ^ 1][0] + tid * 8;
      bf16* lv = &vt2[cur ^ 1][0] + tid * 8;
      size_t kko = (size_t)(kb + 1) * 64 * 2304;  // next 64 k-rows
      size_t vko = (size_t)(kb + 1) * 4096;
#pragma unroll
      for (int t = 0; t < 2; ++t) {
        async_cp16(kbase + kko + t * 32, lk + t * 2048);
        async_cp16(vbase + vko + (size_t)t * 2048, lv + t * 2048);
      }
    }

    f32x4 sb4[4], sa4[4];
    for (int nt = 0; nt < 4; nt++) {
      for (int r = 0; r < 4; r++) { sb4[nt][r] = -10.f; sa4[nt][r] = -10.f; }
      for (int ks = 0; ks < 2; ks++) {
        sb4[nt] = __builtin_amdgcn_mfma_f32_16x16x32_bf16(kf[ks][nt], qfb[ks],
                                                          sb4[nt], 0, 0, 0);
        if (act_a)
          sa4[nt] = __builtin_amdgcn_mfma_f32_16x16x32_bf16(kf[ks][nt], qfa[ks],
                                                            sa4[nt], 0, 0, 0);
      }
    }
    if (kb == b) {
      int ql = wave * 16 + l16;
      for (int nt = 0; nt < 4; nt++)
        for (int r = 0; r < 4; r++)
          if (nt * 16 + quad * 4 + r > ql) sb4[nt][r] = -INFINITY;
    }
    if (kb == a) {
      int ql = wave * 16 + l16;
      for (int nt = 0; nt < 4; nt++)
        for (int r = 0; r < 4; r++)
          if (nt * 16 + quad * 4 + r > ql) sa4[nt][r] = -INFINITY;
    }

    float rsb = 0.f;
    for (int nt = 0; nt < 4; nt++)
      for (int r = 0; r < 4; r++) {
        float p = __expf(sb4[nt][r]);
        sb4[nt][r] = p;
        rsb += p;
      }
    rsb += __shfl_xor(rsb, 16);
    rsb += __shfl_xor(rsb, 32);
    lib += rsb;
    bf16* pwb = pbb[wave];
    for (int nt = 0; nt < 4; nt++) {
      short4v pk;
      for (int r = 0; r < 4; r++)
        pk[r] = __builtin_bit_cast(short, __float2bfloat16(sb4[nt][r]));
      *(short4v*)&pwb[l16 * 68 + nt * 16 + quad * 4] = pk;
    }
    if (act_a) {
      float rsa = 0.f;
      for (int nt = 0; nt < 4; nt++)
        for (int r = 0; r < 4; r++) {
          float p = __expf(sa4[nt][r]);
          sa4[nt][r] = p;
          rsa += p;
        }
      rsa += __shfl_xor(rsa, 16);
      rsa += __shfl_xor(rsa, 32);
      lia += rsa;
      bf16* pwa = pba[wave];
      for (int nt = 0; nt < 4; nt++) {
        short4v pk;
        for (int r = 0; r < 4; r++)
          pk[r] = __builtin_bit_cast(short, __float2bfloat16(sa4[nt][r]));
        *(short4v*)&pwa[l16 * 68 + nt * 16 + quad * 4] = pk;
      }
    }
    asm volatile("s_waitcnt lgkmcnt(0)" ::: "memory");  // same-wave LDS RAW

    for (int ks = 0; ks < 2; ks++) {
      short8 pfb = *(const short8*)&pbb[wave][l16 * 68 + ks * 32 + quad * 8];
      short8 pfa;
      if (act_a) pfa = *(const short8*)&pba[wave][l16 * 68 + ks * 32 + quad * 8];
      for (int dt = 0; dt < 4; dt++) {
        oab[dt] = __builtin_amdgcn_mfma_f32_16x16x32_bf16(vf[ks][dt], pfb,
                                                          oab[dt], 0, 0, 0);
        if (act_a)
          oaa[dt] = __builtin_amdgcn_mfma_f32_16x16x32_bf16(vf[ks][dt], pfa,
                                                            oaa[dt], 0, 0, 0);
      }
    }
  }

  float inva = 1.0f / lia, invb = 1.0f / lib;
  int ta = n * S_LEN + qra + l16;
  int tb = n * S_LEN + qrb + l16;
  for (int dt = 0; dt < 4; dt++) {
    short4v ova, ovb;
    for (int r = 0; r < 4; r++) {
      ova[r] = __builtin_bit_cast(short, __float2bfloat16(oaa[dt][r] * inva));
      ovb[r] = __builtin_bit_cast(short, __float2bfloat16(oab[dt][r] * invb));
    }
    *(short4v*)&out[(size_t)ta * E_DIM + h * 64 + dt * 16 + quad * 4] = ova;
    *(short4v*)&out[(size_t)tb * E_DIM + h * 64 + dt * 16 + quad * 4] = ovb;
  }
}

extern "C" void kernel_launch(void* const* d_in, const int* in_sizes, int n_in,
                              void* d_out, int out_size, void* d_ws, size_t ws_size,
                              hipStream_t stream) {
  (void)in_sizes; (void)n_in; (void)out_size; (void)ws_size;
  const float* x      = (const float*)d_in[0];
  const float* ln1_g  = (const float*)d_in[1];
  const float* ln1_b  = (const float*)d_in[2];
  const float* ln2_g  = (const float*)d_in[3];
  const float* ln2_b  = (const float*)d_in[4];
  const float* w_attn = (const float*)d_in[5];
  const float* b_attn = (const float*)d_in[6];
  const float* w_proj = (const float*)d_in[7];
  const float* b_proj = (const float*)d_in[8];
  const float* w_fc   = (const float*)d_in[9];
  const float* b_fc   = (const float*)d_in[10];
  const float* w_fc2  = (const float*)d_in[11];
  const float* b_fc2  = (const float*)d_in[12];
  float* out = (float*)d_out;

  char* ws = (char*)d_ws;
  bf16* wt_attn = (bf16*)(ws);                 //  3,538,944 B
  bf16* wt_proj = (bf16*)(ws + 3538944);       //  1,179,648 B
  bf16* wt_fc   = (bf16*)(ws + 4718592);       //  4,718,592 B
  bf16* wt_fc2  = (bf16*)(ws + 9437184);       //  4,718,592 B
  bf16* hbuf    = (bf16*)(ws + 14155776);      // 12,582,912 B (also ao)
  float* x2     = (float*)(ws + 26738688);     // 25,165,824 B
  bf16* qkvb    = (bf16*)(ws + 51904512);      // 37,748,736 B (linear qkv)
  bf16* vtb     = (bf16*)(ws + 89653248);      // 12,582,912 B (ends 102,236,160)
  bf16* ao      = hbuf;                        // alias: hbuf dead after QKV gemm
  bf16* ff      = qkvb;  // reuse qkv+vtb region (50,331,648 B needed)

  dim3 blk(256);
  wcastT_all<<<dim3(6912), blk, 0, stream>>>(w_attn, w_proj, w_fc, w_fc2,
                                             wt_attn, wt_proj, wt_fc, wt_fc2);

  ln_rows<<<8192, blk, 0, stream>>>(x, ln1_g, ln1_b, hbuf);

  // QKV: M=8192, N=2304, K=768 -> 32 x 18 = 576 blocks of 512 threads
  gemm8<1><<<dim3(576), dim3(512), 0, stream>>>(
      hbuf, wt_attn, b_attn, qkvb, 8192, 2304, 768);

  scatter_v<<<dim3(1024), blk, 0, stream>>>(qkvb, vtb);

  attn_fwd<<<dim3(768), blk, 0, stream>>>(qkvb, vtb, ao);

  gemm_bt64<<<dim3(12 * 64), blk, 0, stream>>>(
      ao, wt_proj, b_proj, x, x2, 8192, 768, 768);

  ln_rows<<<8192, blk, 0, stream>>>(x2, ln2_g, ln2_b, hbuf);

  // FC1: M=8192, N=3072, K=768 -> 32 x 24 = 768 blocks
  gemm8<2><<<dim3(768), dim3(512), 0, stream>>>(
      hbuf, wt_fc, b_fc, ff, 8192, 3072, 768);

  gemm_bt64<<<dim3(12 * 64), blk, 0, stream>>>(
      ff, wt_fc2, b_fc2, x2, out, 8192, 768, 3072);
}

// Round 5
// 345.171 us; speedup vs baseline: 1.0973x; 1.0448x over previous
//
#include <hip/hip_runtime.h>
#include <hip/hip_bf16.h>
#include <stdint.h>

#define S_LEN 1024
#define E_DIM 768
#define H_N   12
#define FF_DIM 3072

typedef __hip_bfloat16 bf16;
using short8  = __attribute__((ext_vector_type(8))) short;
using short4v = __attribute__((ext_vector_type(4))) short;
using f32x4   = __attribute__((ext_vector_type(4))) float;

__device__ __forceinline__ void async_cp16(const void* g, void* l) {
  __builtin_amdgcn_global_load_lds(
      (__attribute__((address_space(1))) void*)(g),
      (__attribute__((address_space(3))) void*)(l), 16, 0, 0);
}

// -------- fused weight transpose + cast (all 4 weights, one launch) ----------
__global__ __launch_bounds__(256) void wcastT_all(
    const float* __restrict__ wa, const float* __restrict__ wp,
    const float* __restrict__ wf, const float* __restrict__ wf2,
    bf16* __restrict__ oa, bf16* __restrict__ op,
    bf16* __restrict__ of, bf16* __restrict__ of2) {
  __shared__ float t[32][33];
  int bid = blockIdx.x;
  const float* w; bf16* wt; int K, N, bx, by;
  if (bid < 1728)      { w = wa;  wt = oa;  K = 768;  N = 2304; int r = bid;        bx = r % 72; by = r / 72; }
  else if (bid < 2304) { w = wp;  wt = op;  K = 768;  N = 768;  int r = bid - 1728; bx = r % 24; by = r / 24; }
  else if (bid < 4608) { w = wf;  wt = of;  K = 768;  N = 3072; int r = bid - 2304; bx = r % 96; by = r / 96; }
  else                 { w = wf2; wt = of2; K = 3072; N = 768;  int r = bid - 4608; bx = r % 24; by = r / 24; }
  int x = threadIdx.x & 31;
  int y = threadIdx.x >> 5;     // 0..7
  for (int i = y; i < 32; i += 8)
    t[i][x] = w[(size_t)(by * 32 + i) * N + bx * 32 + x];
  __syncthreads();
  for (int i = y; i < 32; i += 8)
    wt[(size_t)(bx * 32 + i) * K + by * 32 + x] = __float2bfloat16(t[x][i]);
}

// ---------------- layernorm over E=768, out bf16 -----------------------------
__global__ __launch_bounds__(256) void ln_rows(const float* __restrict__ x,
                                               const float* __restrict__ g,
                                               const float* __restrict__ b,
                                               bf16* __restrict__ out) {
  int row = blockIdx.x;
  int tid = threadIdx.x;
  const float* xr = x + (size_t)row * E_DIM;
  float v0 = xr[tid], v1 = xr[tid + 256], v2 = xr[tid + 512];
  float s = v0 + v1 + v2;
  float ss = v0 * v0 + v1 * v1 + v2 * v2;
  for (int o = 32; o > 0; o >>= 1) {
    s  += __shfl_down(s, o);
    ss += __shfl_down(ss, o);
  }
  __shared__ float ps[4], pq[4];
  int wv = tid >> 6;
  if ((tid & 63) == 0) { ps[wv] = s; pq[wv] = ss; }
  __syncthreads();
  s  = ps[0] + ps[1] + ps[2] + ps[3];
  ss = pq[0] + pq[1] + pq[2] + pq[3];
  float mu  = s * (1.0f / E_DIM);
  float var = ss * (1.0f / E_DIM) - mu * mu;
  float rs  = rsqrtf(var + 1e-5f);
  bf16* orow = out + (size_t)row * E_DIM;
  orow[tid]       = __float2bfloat16((v0 - mu) * rs * g[tid]       + b[tid]);
  orow[tid + 256] = __float2bfloat16((v1 - mu) * rs * g[tid + 256] + b[tid + 256]);
  orow[tid + 512] = __float2bfloat16((v2 - mu) * rs * g[tid + 512] + b[tid + 512]);
}

// ---------------- V scatter: linear qkv -> vtb transposed layout -------------
__global__ __launch_bounds__(256) void scatter_v(const bf16* __restrict__ qkv,
                                                 bf16* __restrict__ vtb) {
  int blk = blockIdx.x;          // 1024 = n(8) x soct(128)
  int n = blk >> 7, soct = blk & 127;
  int tid = threadIdx.x;
  for (int j = tid; j < 768; j += 256) {
    int h = j >> 6, d = j & 63;
    const bf16* src = qkv + ((size_t)(n * 1024 + soct * 8)) * 2304 + 1536 + h * 64 + d;
    short8 v;
#pragma unroll
    for (int i = 0; i < 8; i++)
      v[i] = __builtin_bit_cast(short, src[(size_t)i * 2304]);
    *(short8*)&vtb[((((size_t)n * 12 + h) * 128 + soct) * 64 + d) * 8] = v;
  }
}

// ---------------- GEMM 256x128 4-phase 8-wave, C = A @ Bt^T ------------------
// 512 threads = 8 waves (2M x 4N), per-wave 128x32 output. BK=64, 2 K-tiles
// per iter in 4 phases of 16 MFMA; counted vmcnt(4), never 0 in steady state.
// XOR swizzle on GLOBAL source, linear LDS dest (global_load_lds).
// Epilogue: LDS-bounce transpose (LDS dead after the loop) so every global
// store instruction writes 16 complete 64B lines (4 lanes x 16B per line) —
// kills the write-allocate RMW fetch (~output-size of extra HBM FETCH seen
// with the old 8B row-scattered stores).
// MODE 1: linear bf16 + bias, cols<768 scaled 0.125 (qkv). MODE 2: gelu.
template <int MODE>
__global__ __launch_bounds__(512, 2) void gemm8(
    const bf16* __restrict__ A, const bf16* __restrict__ Bt,
    const float* __restrict__ bias, bf16* __restrict__ outb,
    int M, int N, int K) {
  __shared__ __align__(16) bf16 smem[49152];   // 96 KB
  bf16 (*lA)[16384] = reinterpret_cast<bf16(*)[16384]>(smem);          // 2x32KB
  bf16 (*lB)[8192]  = reinterpret_cast<bf16(*)[8192]>(smem + 32768);   // 2x16KB
  int tid = threadIdx.x;
  int w = tid >> 6, lane = tid & 63;
  int quad = lane >> 4, l16 = lane & 15;
  int wr = w >> 2, wc = w & 3;    // wave rows wr*128..+128, cols wc*32..+32
  int gx = N >> 7;
  int flat = blockIdx.x;
  int y8 = flat & 7;
  int q2 = flat >> 3;
  int bx = q2 % gx;
  int by = (q2 / gx) * 8 + y8;
  int m0 = by << 8, n0 = bx << 7;

  f32x4 acc[8][2];
#pragma unroll
  for (int i = 0; i < 8; i++)
#pragma unroll
    for (int j = 0; j < 2; j++)
#pragma unroll
      for (int r = 0; r < 4; r++) acc[i][j][r] = 0.f;

  int xs = l16 & 7;                       // fragment-read XOR key (row&7)
  int ko0 = (quad ^ xs) << 3;             // ks=0 swizzled col offset (elems)
  int ko1 = ((4 + quad) ^ xs) << 3;       // ks=1
  int sgo = ((tid & 7) ^ ((tid >> 3) & 7)) << 3;  // staging src col (elems)
  size_t aRB = (size_t)(m0 + (tid >> 3)) * K + sgo;
  size_t bRB = (size_t)(n0 + (tid >> 3)) * K + sgo;
  int aD = tid * 8;                       // A LDS dest base (elems)
  int bD = tid * 8;                       // B LDS dest base (elems)

  // Stage A stripe-pair mh: global rows {m0 + p*128 + mh*64 + [0,64)}, p=0,1
  auto stA = [&](int buf, int mh, int kt) {
#pragma unroll
    for (int p = 0; p < 2; ++p)
      async_cp16(A + aRB + (size_t)(p * 128 + mh * 64) * K + (size_t)kt * 64,
                 &lA[buf][aD + mh * 4096 + p * 8192]);
  };
  // Stage whole B tile: rows n0 + p*64 + [0,64)
  auto stB = [&](int buf, int kt) {
#pragma unroll
    for (int p = 0; p < 2; ++p)
      async_cp16(Bt + bRB + (size_t)(p * 64) * K + (size_t)kt * 64,
                 &lB[buf][bD + p * 4096]);
  };

  short8 af[4][2], bf[2][2];

#define LD_A(BUF, MH)                                                        \
  {                                                                          \
    _Pragma("unroll") for (int i = 0; i < 4; ++i) {                          \
      const bf16* bp =                                                       \
          &lA[BUF][(MH)*4096 + wr * 8192 + (i * 16 + l16) * 64];             \
      af[i][0] = *(const short8*)&bp[ko0];                                   \
      af[i][1] = *(const short8*)&bp[ko1];                                   \
    }                                                                        \
  }
#define LD_B(BUF)                                                            \
  {                                                                          \
    _Pragma("unroll") for (int j = 0; j < 2; ++j) {                          \
      int rb = wc * 32 + j * 16 + l16;                                       \
      const bf16* bp = &lB[BUF][((rb >> 6) << 12) + ((rb & 63) << 6)];       \
      bf[j][0] = *(const short8*)&bp[ko0];                                   \
      bf[j][1] = *(const short8*)&bp[ko1];                                   \
    }                                                                        \
  }
#define DO_MFMA(MH)                                                          \
  {                                                                          \
    __builtin_amdgcn_s_setprio(1);                                           \
    _Pragma("unroll") for (int ks = 0; ks < 2; ++ks)                         \
        _Pragma("unroll") for (int i = 0; i < 4; ++i)                        \
            _Pragma("unroll") for (int j = 0; j < 2; ++j)                    \
                acc[(MH)*4 + i][j] =                                         \
        __builtin_amdgcn_mfma_f32_16x16x32_bf16(                             \
            bf[j][ks], af[i][ks], acc[(MH)*4 + i][j], 0, 0, 0);              \
    __builtin_amdgcn_s_setprio(0);                                           \
  }
#define BAR() __builtin_amdgcn_s_barrier()
#define LGKM0() asm volatile("s_waitcnt lgkmcnt(0)" ::: "memory")
#define VM4() asm volatile("s_waitcnt vmcnt(4)" ::: "memory")
#define VM0() asm volatile("s_waitcnt vmcnt(0)" ::: "memory")

  // prologue: buf0 = tile0 full (6 ops); buf1 = tile1 {A-mh0, B} (4 ops)
  stA(0, 0, 0); stA(0, 1, 0); stB(0, 0);
  stA(1, 0, 1); stB(1, 1);
  VM4();   // drains buf0's 6; buf1's 4 stay in flight
  BAR();

  int nit = K >> 7;   // 2 K-tiles per iteration (K % 128 == 0)
  for (int it = 0; it < nit; ++it) {
    int ktA = 2 * it + 2, ktB = 2 * it + 3;
    bool more = (it + 1 < nit);
    // ph1: buf0.mh0 | stage buf1.A-mh1 (current tile 2it+1, last piece)
    LD_A(0, 0); LD_B(0);
    stA(1, 1, 2 * it + 1);
    BAR(); LGKM0(); DO_MFMA(0); BAR();
    // ph2: buf0.mh1 (bf kept) | stage buf0.{A-mh0,B} <- ktA; drain to 4
    LD_A(0, 1);
    if (more) { stA(0, 0, ktA); stB(0, ktA); VM4(); } else { VM0(); }
    BAR(); LGKM0(); DO_MFMA(1); BAR();
    // ph3: buf1.mh0 | stage buf0.A-mh1 <- ktA
    LD_A(1, 0); LD_B(1);
    if (more) stA(0, 1, ktA);
    BAR(); LGKM0(); DO_MFMA(0); BAR();
    // ph4: buf1.mh1 (bf kept) | stage buf1.{A-mh0,B} <- ktB; drain to 4
    LD_A(1, 1);
    if (more) { stA(1, 0, ktB); stB(1, ktB); VM4(); }
    BAR(); LGKM0(); DO_MFMA(1); BAR();
  }

  // ---- LDS-bounce epilogue (LDS dead after final barrier) ----
  // Per-wave private region: 128 rows x stride 40 bf16 = 10240 B (8 waves =
  // 80 KB <= 96 KB). Same-wave RAW only -> lgkmcnt, no barrier.
  {
    bf16* wbuf = smem + w * 5120;
#pragma unroll
    for (int nj = 0; nj < 2; ++nj) {
      int lc = nj * 16 + quad * 4;
      int colb = n0 + wc * 32 + lc;
      f32x4 b4 = *(const f32x4*)&bias[colb];
      float sc = (MODE == 1 && colb < 768) ? 0.125f : 1.0f;
#pragma unroll
      for (int mi = 0; mi < 8; ++mi) {
        f32x4 v = acc[mi][nj] + b4;
        short4v pk;
        if (MODE == 1) {
          for (int r = 0; r < 4; r++)
            pk[r] = __builtin_bit_cast(short, __float2bfloat16(v[r] * sc));
        } else {
          for (int r = 0; r < 4; r++) {
            float x = v[r];
            // tanh-form GELU: x * sigmoid(1.5957691*(x + 0.044715 x^3))
            float t = x * (1.59576912161f + 0.0713548162726f * x * x);
            float g = x * __builtin_amdgcn_rcpf(1.0f + __expf(-t));
            pk[r] = __builtin_bit_cast(short, __float2bfloat16(g));
          }
        }
        *(short4v*)&wbuf[(mi * 16 + l16) * 40 + lc] = pk;
      }
    }
    asm volatile("s_waitcnt lgkmcnt(0)" ::: "memory");
    // read back 16B/lane; 4 consecutive lanes = one full 64B line
#pragma unroll
    for (int p = 0; p < 8; ++p) {
      int chunk = p * 64 + lane;
      int r = chunk >> 2, c8 = (chunk & 3) * 8;
      short8 vv = *(const short8*)&wbuf[r * 40 + c8];
      *(short8*)&outb[(size_t)(m0 + wr * 128 + r) * N + n0 + wc * 32 + c8] = vv;
    }
  }
#undef LD_A
#undef LD_B
#undef DO_MFMA
#undef BAR
#undef LGKM0
#undef VM4
#undef VM0
}

// ---------------- GEMM 128x64: outf = A@Bt^T + bias + resid ------------------
__global__ __launch_bounds__(256) void gemm_bt64(
    const bf16* __restrict__ A, const bf16* __restrict__ Bt,
    const float* __restrict__ bias, const float* __restrict__ resid,
    float* __restrict__ outf, int M, int N, int K) {
  __shared__ bf16 As[2][128 * 64];   // 2 x 16 KB
  __shared__ bf16 Bs[2][64 * 64];    // 2 x  8 KB
  int tid = threadIdx.x;
  int wave = tid >> 6, lane = tid & 63;
  int quad = lane >> 4, l16 = lane & 15;
  int gx = N >> 6;                  // 12
  int flat = blockIdx.x;
  int y8 = flat & 7;
  int q2 = flat >> 3;
  int bx = q2 % gx;
  int by = (q2 / gx) * 8 + y8;
  int m0 = by * 128, n0 = bx * 64;
  int wm = wave * 32;               // wave owns 32 M-rows, all 64 N-cols
  f32x4 acc[2][4];
  for (int i = 0; i < 2; i++)
    for (int j = 0; j < 4; j++)
      for (int r = 0; r < 4; r++) acc[i][j][r] = 0.f;

  int xs = l16 & 7;
  int srow = tid >> 3;
  int scg = (((tid & 7) ^ (srow & 7)) << 3);
  const bf16* aptr = A  + (size_t)(m0 + srow) * K + scg;
  const bf16* bptr = Bt + (size_t)(n0 + srow) * K + scg;
  int ldst = tid * 8;

#pragma unroll
  for (int t = 0; t < 4; t++)
    async_cp16(aptr + (size_t)t * 32 * K, &As[0][ldst + t * 2048]);
#pragma unroll
  for (int t = 0; t < 2; t++)
    async_cp16(bptr + (size_t)t * 32 * K, &Bs[0][ldst + t * 2048]);

  int nkb = K >> 6;
  for (int ik = 0; ik < nkb; ++ik) {
    int cur = ik & 1;
    if (ik + 1 < nkb) {
      size_t ko = (size_t)(ik + 1) * 64;
#pragma unroll
      for (int t = 0; t < 4; t++)
        async_cp16(aptr + ko + (size_t)t * 32 * K, &As[cur ^ 1][ldst + t * 2048]);
#pragma unroll
      for (int t = 0; t < 2; t++)
        async_cp16(bptr + ko + (size_t)t * 32 * K, &Bs[cur ^ 1][ldst + t * 2048]);
      asm volatile("s_waitcnt vmcnt(6)" ::: "memory");
    } else {
      asm volatile("s_waitcnt vmcnt(0)" ::: "memory");
    }
    __builtin_amdgcn_s_barrier();
    asm volatile("" ::: "memory");
#pragma unroll
    for (int ks = 0; ks < 2; ks++) {
      int ko2 = (((ks * 4 + quad) ^ xs) << 3);
      short8 af[2], bfr[4];
      for (int i = 0; i < 2; i++)
        af[i] = *(const short8*)&As[cur][(wm + i * 16 + l16) * 64 + ko2];
      for (int j = 0; j < 4; j++)
        bfr[j] = *(const short8*)&Bs[cur][(j * 16 + l16) * 64 + ko2];
      for (int i = 0; i < 2; i++)
        for (int j = 0; j < 4; j++)
          acc[i][j] = __builtin_amdgcn_mfma_f32_16x16x32_bf16(
              bfr[j], af[i], acc[i][j], 0, 0, 0);
    }
    asm volatile("" ::: "memory");
    __builtin_amdgcn_s_barrier();
  }

  for (int j = 0; j < 4; j++) {
    int colb = n0 + j * 16 + quad * 4;
    f32x4 b4 = *(const f32x4*)&bias[colb];
    for (int i = 0; i < 2; i++) {
      int row = m0 + wm + i * 16 + l16;
      size_t idx = (size_t)row * N + colb;
      f32x4 rv = *(const f32x4*)&resid[idx];
      *(f32x4*)&outf[idx] = acc[i][j] + b4 + rv;
    }
  }
}

// ---------------- flash attention: paired q-tiles, pipelined K/V -------------
// Q and K read directly from linear qkv [8192 x 2304] (Q pre-scaled 0.125);
// V from vtb transposed layout.
__global__ __launch_bounds__(256) void attn_fwd(
    const bf16* __restrict__ qkv, const bf16* __restrict__ vg,
    bf16* __restrict__ out) {
  __shared__ bf16 kt2[2][8 * 64 * 8];  // 16 KB
  __shared__ bf16 vt2[2][8 * 64 * 8];  // 16 KB
  __shared__ bf16 pba[4][16 * 68];     // per-wave P, tile a (8.5 KB)
  __shared__ bf16 pbb[4][16 * 68];     // per-wave P, tile b (8.5 KB)
  int flat = blockIdx.x;             // 768 blocks
  int xcd = flat & 7;
  int j = flat >> 3;                 // 0..95
  int a = j & 7;                     // low q-tile 0..7
  int g = j >> 3;                    // 0..11
  int nh = xcd * 12 + g;             // head: all its blocks share flat&7
  int b = 15 - a;                    // high q-tile 8..15
  int n = nh / H_N, h = nh % H_N;
  int tid = threadIdx.x, wave = tid >> 6, lane = tid & 63;
  int quad = lane >> 4, l16 = lane & 15;
  const bf16* qp = qkv + (size_t)n * S_LEN * 2304 + (size_t)h * 64;
  const bf16* vp = vg + (size_t)nh * 128 * 64 * 8;
  int qra = a * 64 + wave * 16;      // tile-a wave rows; lane's q = qra + l16
  int qrb = b * 64 + wave * 16;

  short8 qfa[2], qfb[2];
  qfa[0] = *(const short8*)&qp[(size_t)(qra + l16) * 2304 + quad * 8];
  qfa[1] = *(const short8*)&qp[(size_t)(qra + l16) * 2304 + 32 + quad * 8];
  qfb[0] = *(const short8*)&qp[(size_t)(qrb + l16) * 2304 + quad * 8];
  qfb[1] = *(const short8*)&qp[(size_t)(qrb + l16) * 2304 + 32 + quad * 8];

  // K staging: slot = t*256+tid -> c-octet = t*4+(tid>>6), krow = tid&63
  const bf16* kbase = qkv + ((size_t)n * S_LEN + (tid & 63)) * 2304 + 768 +
                      h * 64 + ((tid >> 6) << 3);
  const bf16* vbase = vp + (((size_t)(tid >> 6) * 64) + (tid & 63)) * 8;

  f32x4 oaa[4], oab[4];              // O^T: d = dt*16+quad*4+r, q = l16
  for (int dt = 0; dt < 4; dt++)
    for (int r = 0; r < 4; r++) { oaa[dt][r] = 0.f; oab[dt][r] = 0.f; }
  float lia = 0.f, lib = 0.f;

  {
    bf16* lk = &kt2[0][0] + tid * 8;
    bf16* lv = &vt2[0][0] + tid * 8;
#pragma unroll
    for (int t = 0; t < 2; ++t) {
      async_cp16(kbase + t * 32, lk + t * 2048);
      async_cp16(vbase + (size_t)t * 2048, lv + t * 2048);
    }
  }

  for (int kb = 0; kb <= b; ++kb) {
    bool act_a = (kb <= a);
    int cur = kb & 1;
    __syncthreads();   // drains prefetch issued last iteration

    short8 kf[2][4], vf[2][4];
#pragma unroll
    for (int ks = 0; ks < 2; ks++)
      for (int nt = 0; nt < 4; nt++) {
        kf[ks][nt] = *(const short8*)
            &kt2[cur][(size_t)((ks * 4 + quad) * 64 + nt * 16 + l16) * 8];
        vf[ks][nt] = *(const short8*)
            &vt2[cur][(size_t)((ks * 4 + quad) * 64 + nt * 16 + l16) * 8];
      }
    if (kb < b) {
      bf16* lk = &kt2[cur ^ 1][0] + tid * 8;
      bf16* lv = &vt2[cur ^ 1][0] + tid * 8;
      size_t kko = (size_t)(kb + 1) * 64 * 2304;  // next 64 k-rows
      size_t vko = (size_t)(kb + 1) * 4096;
#pragma unroll
      for (int t = 0; t < 2; ++t) {
        async_cp16(kbase + kko + t * 32, lk + t * 2048);
        async_cp16(vbase + vko + (size_t)t * 2048, lv + t * 2048);
      }
    }

    f32x4 sb4[4], sa4[4];
    for (int nt = 0; nt < 4; nt++) {
      for (int r = 0; r < 4; r++) { sb4[nt][r] = -10.f; sa4[nt][r] = -10.f; }
      for (int ks = 0; ks < 2; ks++) {
        sb4[nt] = __builtin_amdgcn_mfma_f32_16x16x32_bf16(kf[ks][nt], qfb[ks],
                                                          sb4[nt], 0, 0, 0);
        if (act_a)
          sa4[nt] = __builtin_amdgcn_mfma_f32_16x16x32_bf16(kf[ks][nt], qfa[ks],
                                                            sa4[nt], 0, 0, 0);
      }
    }
    if (kb == b) {
      int ql = wave * 16 + l16;
      for (int nt = 0; nt < 4; nt++)
        for (int r = 0; r < 4; r++)
          if (nt * 16 + quad * 4 + r > ql) sb4[nt][r] = -INFINITY;
    }
    if (kb == a) {
      int ql = wave * 16 + l16;
      for (int nt = 0; nt < 4; nt++)
        for (int r = 0; r < 4; r++)
          if (nt * 16 + quad * 4 + r > ql) sa4[nt][r] = -INFINITY;
    }

    float rsb = 0.f;
    for (int nt = 0; nt < 4; nt++)
      for (int r = 0; r < 4; r++) {
        float p = __expf(sb4[nt][r]);
        sb4[nt][r] = p;
        rsb += p;
      }
    rsb += __shfl_xor(rsb, 16);
    rsb += __shfl_xor(rsb, 32);
    lib += rsb;
    bf16* pwb = pbb[wave];
    for (int nt = 0; nt < 4; nt++) {
      short4v pk;
      for (int r = 0; r < 4; r++)
        pk[r] = __builtin_bit_cast(short, __float2bfloat16(sb4[nt][r]));
      *(short4v*)&pwb[l16 * 68 + nt * 16 + quad * 4] = pk;
    }
    if (act_a) {
      float rsa = 0.f;
      for (int nt = 0; nt < 4; nt++)
        for (int r = 0; r < 4; r++) {
          float p = __expf(sa4[nt][r]);
          sa4[nt][r] = p;
          rsa += p;
        }
      rsa += __shfl_xor(rsa, 16);
      rsa += __shfl_xor(rsa, 32);
      lia += rsa;
      bf16* pwa = pba[wave];
      for (int nt = 0; nt < 4; nt++) {
        short4v pk;
        for (int r = 0; r < 4; r++)
          pk[r] = __builtin_bit_cast(short, __float2bfloat16(sa4[nt][r]));
        *(short4v*)&pwa[l16 * 68 + nt * 16 + quad * 4] = pk;
      }
    }
    asm volatile("s_waitcnt lgkmcnt(0)" ::: "memory");  // same-wave LDS RAW

    for (int ks = 0; ks < 2; ks++) {
      short8 pfb = *(const short8*)&pbb[wave][l16 * 68 + ks * 32 + quad * 8];
      short8 pfa;
      if (act_a) pfa = *(const short8*)&pba[wave][l16 * 68 + ks * 32 + quad * 8];
      for (int dt = 0; dt < 4; dt++) {
        oab[dt] = __builtin_amdgcn_mfma_f32_16x16x32_bf16(vf[ks][dt], pfb,
                                                          oab[dt], 0, 0, 0);
        if (act_a)
          oaa[dt] = __builtin_amdgcn_mfma_f32_16x16x32_bf16(vf[ks][dt], pfa,
                                                            oaa[dt], 0, 0, 0);
      }
    }
  }

  float inva = 1.0f / lia, invb = 1.0f / lib;
  int ta = n * S_LEN + qra + l16;
  int tb = n * S_LEN + qrb + l16;
  for (int dt = 0; dt < 4; dt++) {
    short4v ova, ovb;
    for (int r = 0; r < 4; r++) {
      ova[r] = __builtin_bit_cast(short, __float2bfloat16(oaa[dt][r] * inva));
      ovb[r] = __builtin_bit_cast(short, __float2bfloat16(oab[dt][r] * invb));
    }
    *(short4v*)&out[(size_t)ta * E_DIM + h * 64 + dt * 16 + quad * 4] = ova;
    *(short4v*)&out[(size_t)tb * E_DIM + h * 64 + dt * 16 + quad * 4] = ovb;
  }
}

extern "C" void kernel_launch(void* const* d_in, const int* in_sizes, int n_in,
                              void* d_out, int out_size, void* d_ws, size_t ws_size,
                              hipStream_t stream) {
  (void)in_sizes; (void)n_in; (void)out_size; (void)ws_size;
  const float* x      = (const float*)d_in[0];
  const float* ln1_g  = (const float*)d_in[1];
  const float* ln1_b  = (const float*)d_in[2];
  const float* ln2_g  = (const float*)d_in[3];
  const float* ln2_b  = (const float*)d_in[4];
  const float* w_attn = (const float*)d_in[5];
  const float* b_attn = (const float*)d_in[6];
  const float* w_proj = (const float*)d_in[7];
  const float* b_proj = (const float*)d_in[8];
  const float* w_fc   = (const float*)d_in[9];
  const float* b_fc   = (const float*)d_in[10];
  const float* w_fc2  = (const float*)d_in[11];
  const float* b_fc2  = (const float*)d_in[12];
  float* out = (float*)d_out;

  char* ws = (char*)d_ws;
  bf16* wt_attn = (bf16*)(ws);                 //  3,538,944 B
  bf16* wt_proj = (bf16*)(ws + 3538944);       //  1,179,648 B
  bf16* wt_fc   = (bf16*)(ws + 4718592);       //  4,718,592 B
  bf16* wt_fc2  = (bf16*)(ws + 9437184);       //  4,718,592 B
  bf16* hbuf    = (bf16*)(ws + 14155776);      // 12,582,912 B (also ao)
  float* x2     = (float*)(ws + 26738688);     // 25,165,824 B
  bf16* qkvb    = (bf16*)(ws + 51904512);      // 37,748,736 B (linear qkv)
  bf16* vtb     = (bf16*)(ws + 89653248);      // 12,582,912 B (ends 102,236,160)
  bf16* ao      = hbuf;                        // alias: hbuf dead after QKV gemm
  bf16* ff      = qkvb;  // reuse qkv+vtb region (50,331,648 B needed)

  dim3 blk(256);
  wcastT_all<<<dim3(6912), blk, 0, stream>>>(w_attn, w_proj, w_fc, w_fc2,
                                             wt_attn, wt_proj, wt_fc, wt_fc2);

  ln_rows<<<8192, blk, 0, stream>>>(x, ln1_g, ln1_b, hbuf);

  // QKV: M=8192, N=2304, K=768 -> 32 x 18 = 576 blocks of 512 threads
  gemm8<1><<<dim3(576), dim3(512), 0, stream>>>(
      hbuf, wt_attn, b_attn, qkvb, 8192, 2304, 768);

  scatter_v<<<dim3(1024), blk, 0, stream>>>(qkvb, vtb);

  attn_fwd<<<dim3(768), blk, 0, stream>>>(qkvb, vtb, ao);

  gemm_bt64<<<dim3(12 * 64), blk, 0, stream>>>(
      ao, wt_proj, b_proj, x, x2, 8192, 768, 768);

  ln_rows<<<8192, blk, 0, stream>>>(x2, ln2_g, ln2_b, hbuf);

  // FC1: M=8192, N=3072, K=768 -> 32 x 24 = 768 blocks
  gemm8<2><<<dim3(768), dim3(512), 0, stream>>>(
      hbuf, wt_fc, b_fc, ff, 8192, 3072, 768);

  gemm_bt64<<<dim3(12 * 64), blk, 0, stream>>>(
      ff, wt_fc2, b_fc2, x2, out, 8192, 768, 3072);
}